// Round 5
// baseline (425.092 us; speedup 1.0000x reference)
//
#include <hip/hip_runtime.h>

// ---------------------------------------------------------------------------
// Attention_20117626815094: c_t[b,t,d] = sum_e softmax_t(enc@dec^T)[e,t] * enc[e,d]
//   B=8, S_ENC=2048, S_DEC=2048, D=1024, fp32 in/out. f16 MFMA compute.
// Pipeline (v8 — v7 + f16-consistent fused stats; 5 kernels):
//   1. conv_enc:  enc fp32 -> enc_h [e][d] f16 AND enc_hT [d][e] f16
//   2. conv_dec:  dec fp32 -> dec_h [t][d] f16
//   3. gemm8p<STATS>: ST[t][e] = dec_h @ enc_h^T; epilogue emits per-block
//      column softmax partials (m, sum) computed from the F16-ROUNDED accs
//      (bit-identical to the ST values gemm2 reads -> self-normalizing
//      softmax, same numerics as the v6 separate-pass pipeline)
//   4. stats_combine: merge 8 t-slice partials -> stats[b][e] = (m, 1/sum)
//   5. gemm8p<NORM>:  out[t][d] = exp(ST-m_e)*rl_e @ enc_hT^T-form
//      (A-operand reg-staged: load ST, apply softmax scale, ds_write to LDS)
// ---------------------------------------------------------------------------

typedef _Float16 half8 __attribute__((ext_vector_type(8)));
typedef _Float16 half4v __attribute__((ext_vector_type(4)));
typedef float floatx4 __attribute__((ext_vector_type(4)));

__device__ __forceinline__ void async_load16(const _Float16* g, void* l) {
  __builtin_amdgcn_global_load_lds(
      (const __attribute__((address_space(1))) void*)g,
      (__attribute__((address_space(3))) void*)l, 16, 0, 0);
}

// ---- 256x256 8-phase pipelined GEMM: C = A @ Bt^T --------------------------
// A[M][K], Bt[N][K] row-major f16, k contiguous. C row-major OutT.
// 512 threads = 8 waves (2m x 4n); per-wave 128x64 out; BK=64; LDS 128 KiB.
// Swizzle: 16B chunk ck of row stored at ck^(row&7); frag reads use per-lane
// bases lb0/lb1 (all XOR folded), frag = +q*2048.
// Phases (quadrant order (0,0)(0,1)(1,1)(1,0); b0 regs live P1->P4):
//   P1: issue a-lo + b0 + b1 reads; mm(0,0)
//   P2: (no reads);                 mm(0,1)   [consumes a-lo, b1]
//   P3: issue a-hi; [NORM: load ST+stats regs] stage next B; mm(1,1)
//   P4: stage/write next A;         mm(1,0); counted vmcnt
// NORM: A-operand is exp(ST-m_e)*rl_e, reg-staged (global->reg->exp->ds_write)
// STATS: epilogue writes per-block column (max, sumexp) partials
template <typename OutT, bool NORM, bool STATS>
__global__ __launch_bounds__(512, 2) void gemm8p(
    const _Float16* __restrict__ A, const _Float16* __restrict__ Bt,
    OutT* __restrict__ C, const float2* __restrict__ st_in,
    float2* __restrict__ part_out, int K, long strideA, long strideB,
    long strideC, int ldA, int ldB, int ldC) {
  extern __shared__ char smem_[];
  const int tid = threadIdx.x;
  const int lane = tid & 63;
  const int wave = tid >> 6;
  const int wm = wave >> 2;  // 0..1
  const int wn = wave & 3;   // 0..3
  const int l15 = lane & 15;
  const int lh = lane >> 4;  // 0..3

  // XCD swizzle over the flat grid (nwg % 8 == 0)
  const int gx = gridDim.x, gxy = gridDim.x * gridDim.y;
  int fid = blockIdx.z * gxy + blockIdx.y * gx + blockIdx.x;
  const int nwg = gxy * gridDim.z;
  fid = (fid & 7) * (nwg >> 3) + (fid >> 3);
  const int b = fid / gxy;
  const int rem = fid - b * gxy;
  const int m0 = (rem / gx) * 256;
  const int n0 = (rem % gx) * 256;

  A += (long)b * strideA + (long)m0 * ldA;
  Bt += (long)b * strideB + (long)n0 * ldB;
  C += (long)b * strideC;
  const float2* statsB = NORM ? st_in + (size_t)b * 2048 : nullptr;

  // precomputed swizzled LDS read bases
  const int lb0 = l15 * 128 + ((lh ^ (l15 & 7)) << 4);
  const int lb1 = lb0 ^ 64;
  const char* aBuf[2] = {smem_ + wm * 16384, smem_ + 32768 + wm * 16384};
  const char* bBuf[2] = {
      smem_ + 65536 + (wn >> 1) * 16384 + (wn & 1) * 8192,
      smem_ + 98304 + (wn >> 1) * 16384 + (wn & 1) * 8192};
  char* aSlot[2] = {smem_, smem_ + 32768};
  char* bSlot[2] = {smem_ + 65536, smem_ + 98304};

  // staging addresses: pre-swizzled global for direct-LDS; linear + swizzled
  // LDS write offset for the reg-staged NORM A-path
  const int srow = tid >> 3;
  const int skk = ((tid & 7) ^ (srow & 7)) << 3;
  const _Float16* Ast = A + (long)srow * ldA + skk;
  const _Float16* Bst = Bt + (long)srow * ldB + skk;
  const _Float16* AstN = A + (long)srow * ldA + ((tid & 7) << 3);
  const int awOff = (srow << 7) + (((tid & 7) ^ (srow & 7)) << 4);
  const int dst = tid << 4;

  floatx4 acc[8][4] = {};
  half8 a[4][2], b0[2][2], b1[2][2];

  auto stage = [&](const _Float16* gs, int ld, int k0, char* slot) {
#pragma unroll
    for (int i = 0; i < 4; ++i)
      async_load16(gs + (long)(i * 64) * ld + k0, slot + i * 8192 + dst);
  };
  auto mm = [&](int mh, int nh, half8(&bb)[2][2]) {
    __builtin_amdgcn_s_setprio(1);
#pragma unroll
    for (int s = 0; s < 2; ++s)
#pragma unroll
      for (int q = 0; q < 4; ++q)
#pragma unroll
        for (int n = 0; n < 2; ++n)
          acc[mh * 4 + q][nh * 2 + n] = __builtin_amdgcn_mfma_f32_16x16x32_f16(
              a[q][s], bb[n][s], acc[mh * 4 + q][nh * 2 + n], 0, 0, 0);
    __builtin_amdgcn_s_setprio(0);
  };
  auto bar = [&]() { asm volatile("s_barrier" ::: "memory"); };

  auto quad4 = [&](int cur, int kst, bool last) {
    const char* aB_ = aBuf[cur];
    const char* bB_ = bBuf[cur];
    half8 stg[4];
    float4 f0_, f1_, f2_, f3_;
    // P1: issue A-low (q=0..3) and ALL B frag reads; compute (0,0)
#pragma unroll
    for (int q = 0; q < 4; ++q) {
      a[q][0] = *(const half8*)(aB_ + lb0 + q * 2048);
      a[q][1] = *(const half8*)(aB_ + lb1 + q * 2048);
    }
#pragma unroll
    for (int n = 0; n < 2; ++n) {
      b0[n][0] = *(const half8*)(bB_ + lb0 + n * 2048);
      b0[n][1] = *(const half8*)(bB_ + lb1 + n * 2048);
      b1[n][0] = *(const half8*)(bB_ + lb0 + (n + 2) * 2048);
      b1[n][1] = *(const half8*)(bB_ + lb1 + (n + 2) * 2048);
    }
    bar();
    mm(0, 0, b0);
    bar();
    // P2: no reads (b1 issued in P1; a-lo still live for mm(0,1))
    bar();
    mm(0, 1, b1);
    bar();
    // P3: issue A-high (a-lo dead after mm(0,1)); stage next-tile B
    //     (B slot fully consumed after P2); NORM: issue ST+stats reg loads
#pragma unroll
    for (int q = 0; q < 4; ++q) {
      a[q][0] = *(const half8*)(aB_ + lb0 + (q + 4) * 2048);
      a[q][1] = *(const half8*)(aB_ + lb1 + (q + 4) * 2048);
    }
    if (kst >= 0) {
      if constexpr (NORM) {
        const float4* sp = (const float4*)(statsB + kst + ((tid & 7) << 3));
        f0_ = sp[0]; f1_ = sp[1]; f2_ = sp[2]; f3_ = sp[3];
#pragma unroll
        for (int i = 0; i < 4; ++i)
          stg[i] = *(const half8*)(AstN + (long)(i * 64) * ldA + kst);
      }
      stage(Bst, ldB, kst, bSlot[cur]);
    }
    bar();
    mm(1, 1, b1);
    bar();
    // P4: produce next-tile A into LDS (A slot fully consumed after P3)
    if constexpr (NORM) {
      if (kst >= 0) {
        const float em[8] = {f0_.x, f0_.z, f1_.x, f1_.z,
                             f2_.x, f2_.z, f3_.x, f3_.z};
        const float er[8] = {f0_.y, f0_.w, f1_.y, f1_.w,
                             f2_.y, f2_.w, f3_.y, f3_.w};
#pragma unroll
        for (int i = 0; i < 4; ++i) {
          half8 v = stg[i];
          half8 o;
#pragma unroll
          for (int j = 0; j < 8; ++j)
            o[j] = (_Float16)(__expf((float)v[j] - em[j]) * er[j]);
          *(half8*)(aSlot[cur] + i * 8192 + awOff) = o;
        }
        mm(1, 0, b0);
        asm volatile("s_waitcnt lgkmcnt(0)" ::: "memory");  // publish ds_writes
      } else {
        mm(1, 0, b0);
        asm volatile("s_waitcnt vmcnt(0)" ::: "memory");
      }
      bar();
    } else {
      if (kst >= 0) stage(Ast, ldA, kst, aSlot[cur]);
      mm(1, 0, b0);
      if (last)
        asm volatile("s_waitcnt vmcnt(0)" ::: "memory");
      else
        asm volatile("s_waitcnt vmcnt(8)" ::: "memory");
      bar();
    }
  };

  // prologue: tiles 0,1 -> bufs 0,1
  if constexpr (NORM) {
    stage(Bst, ldB, 0, bSlot[0]);
    stage(Bst, ldB, 64, bSlot[1]);
#pragma unroll
    for (int t = 0; t < 2; ++t) {
      const int k0 = t * 64;
      const float4* sp = (const float4*)(statsB + k0 + ((tid & 7) << 3));
      float4 f0 = sp[0], f1 = sp[1], f2 = sp[2], f3 = sp[3];
      const float em[8] = {f0.x, f0.z, f1.x, f1.z, f2.x, f2.z, f3.x, f3.z};
      const float er[8] = {f0.y, f0.w, f1.y, f1.w, f2.y, f2.w, f3.y, f3.w};
#pragma unroll
      for (int i = 0; i < 4; ++i) {
        half8 v = *(const half8*)(AstN + (long)(i * 64) * ldA + k0);
        half8 o;
#pragma unroll
        for (int j = 0; j < 8; ++j)
          o[j] = (_Float16)(__expf((float)v[j] - em[j]) * er[j]);
        *(half8*)(aSlot[t] + i * 8192 + awOff) = o;
      }
    }
    asm volatile("s_waitcnt vmcnt(4) lgkmcnt(0)" ::: "memory");
    bar();
  } else {
    stage(Ast, ldA, 0, aSlot[0]);
    stage(Bst, ldB, 0, bSlot[0]);
    stage(Ast, ldA, 64, aSlot[1]);
    stage(Bst, ldB, 64, bSlot[1]);
    asm volatile("s_waitcnt vmcnt(8)" ::: "memory");
    bar();
  }

  const int NT = K >> 6;
  for (int i = 0; i < (NT >> 1) - 1; ++i) {
    quad4(0, (2 * i + 2) * 64, false);
    quad4(1, (2 * i + 3) * 64, false);
  }
  quad4(0, -1, true);
  quad4(1, -1, true);

  // C/D layout (verified): col=lane&15, row=(lane>>4)*4+reg
#pragma unroll
  for (int mf = 0; mf < 8; ++mf) {
    const long r0 = (long)(m0 + wm * 128 + mf * 16 + lh * 4);
#pragma unroll
    for (int nf = 0; nf < 4; ++nf) {
      const int cc = n0 + wn * 64 + nf * 16 + l15;
#pragma unroll
      for (int rr = 0; rr < 4; ++rr)
        C[(r0 + rr) * ldC + cc] = (OutT)acc[mf][nf][rr];
    }
  }

  // Column softmax partials over this block's 256 rows. CRITICAL: compute
  // from the F16-ROUNDED accs so (m, sum) are bit-consistent with the ST
  // values the NORM pass reads back -> softmax self-normalizes (dominant
  // entry: numerator == denominator term, rounding error cancels).
  if constexpr (STATS) {
    float2* sm = (float2*)smem_;
#pragma unroll
    for (int nf = 0; nf < 4; ++nf) {
      float x16[8][4];
#pragma unroll
      for (int mf = 0; mf < 8; ++mf)
#pragma unroll
        for (int rr = 0; rr < 4; ++rr)
          x16[mf][rr] = (float)(_Float16)acc[mf][nf][rr];
      float mx = -1e30f;
#pragma unroll
      for (int mf = 0; mf < 8; ++mf)
#pragma unroll
        for (int rr = 0; rr < 4; ++rr) mx = fmaxf(mx, x16[mf][rr]);
      float ss = 0.f;
#pragma unroll
      for (int mf = 0; mf < 8; ++mf)
#pragma unroll
        for (int rr = 0; rr < 4; ++rr) ss += __expf(x16[mf][rr] - mx);
#pragma unroll
      for (int d = 16; d <= 32; d <<= 1) {
        const float om = __shfl_xor(mx, d, 64);
        const float os = __shfl_xor(ss, d, 64);
        const float m2 = fmaxf(mx, om);
        ss = ss * __expf(mx - m2) + os * __expf(om - m2);
        mx = m2;
      }
      if (lh == 0) sm[wm * 256 + wn * 64 + nf * 16 + l15] = make_float2(mx, ss);
    }
    __syncthreads();
    if (tid < 256) {
      const float2 a0 = sm[tid], a1 = sm[256 + tid];
      const float m2 = fmaxf(a0.x, a1.x);
      const float s2 =
          a0.y * __expf(a0.x - m2) + a1.y * __expf(a1.x - m2);
      part_out[(size_t)(m0 >> 8) * 16384 + (size_t)b * 2048 + n0 + tid] =
          make_float2(m2, s2);
    }
  }
}

// ---- enc convert + transpose (4x4 register micro-transpose) ---------------
__global__ __launch_bounds__(256) void conv_enc(const float* __restrict__ E,
                                                _Float16* __restrict__ Eh,
                                                _Float16* __restrict__ EhT,
                                                int Se, int D) {
  __shared__ _Float16 T[64][72];
  const int b = blockIdx.z;
  const int d0 = blockIdx.x * 64;
  const int e0 = blockIdx.y * 64;
  const float* Eb = E + (size_t)b * Se * D;
  _Float16* Ehb = Eh + (size_t)b * Se * D;
  _Float16* EhTb = EhT + (size_t)b * D * Se;
  const int tid = threadIdx.x;
  const int tx = tid & 15;
  const int ty = tid >> 4;

  half4v h[4];
#pragma unroll
  for (int r = 0; r < 4; ++r) {
    const int e = e0 + ty * 4 + r;
    float4 v = *(const float4*)(Eb + (size_t)e * D + d0 + tx * 4);
    h[r][0] = (_Float16)v.x; h[r][1] = (_Float16)v.y;
    h[r][2] = (_Float16)v.z; h[r][3] = (_Float16)v.w;
    *(half4v*)(Ehb + (size_t)e * D + d0 + tx * 4) = h[r];
  }
#pragma unroll
  for (int c = 0; c < 4; ++c) {
    half4v w;
#pragma unroll
    for (int r = 0; r < 4; ++r) w[r] = h[r][c];
    *(half4v*)&T[tx * 4 + c][ty * 4] = w;
  }
  __syncthreads();
#pragma unroll
  for (int p = 0; p < 2; ++p) {
    const int idx = tid + p * 256;
    const int row = idx >> 3;
    const int ck = idx & 7;
    *(half8*)(EhTb + (size_t)(d0 + row) * Se + e0 + ck * 8) =
        *(const half8*)&T[row][ck * 8];
  }
}

// ---- dec convert (16B stores) ---------------------------------------------
__global__ __launch_bounds__(256) void conv_dec(const float* __restrict__ X,
                                                _Float16* __restrict__ Y) {
  const size_t i = ((size_t)blockIdx.x * 256 + threadIdx.x) * 8;
  float4 a = *(const float4*)(X + i);
  float4 b = *(const float4*)(X + i + 4);
  half8 h;
  h[0] = (_Float16)a.x; h[1] = (_Float16)a.y;
  h[2] = (_Float16)a.z; h[3] = (_Float16)a.w;
  h[4] = (_Float16)b.x; h[5] = (_Float16)b.y;
  h[6] = (_Float16)b.z; h[7] = (_Float16)b.w;
  *(half8*)(Y + i) = h;
}

// ---- merge 8 t-slice partials -> stats = (m, 1/sum) -----------------------
__global__ __launch_bounds__(256) void stats_combine(
    const float2* __restrict__ part, float2* __restrict__ stats) {
  const int idx = blockIdx.x * 256 + threadIdx.x;  // b*2048+e
  float2 a = part[idx];
#pragma unroll
  for (int tc = 1; tc < 8; ++tc) {
    const float2 o = part[tc * 16384 + idx];
    const float m2 = fmaxf(a.x, o.x);
    a.y = a.y * __expf(a.x - m2) + o.y * __expf(o.x - m2);
    a.x = m2;
  }
  stats[idx] = make_float2(a.x, 1.0f / a.y);
}

// ---------------------------------------------------------------------------
extern "C" void kernel_launch(void* const* d_in, const int* in_sizes, int n_in,
                              void* d_out, int out_size, void* d_ws,
                              size_t ws_size, hipStream_t stream) {
  const float* enc = (const float*)d_in[0];
  const float* dec = (const float*)d_in[1];
  float* out = (float*)d_out;

  const int B = 8, SE = 2048, SD = 2048, D = 1024;
  char* ws = (char*)d_ws;
  _Float16* enc_h = (_Float16*)ws;                 // 32 MiB
  _Float16* dec_h = (_Float16*)(ws + 33554432);    // 32 MiB
  _Float16* enc_hT = (_Float16*)(ws + 67108864);   // 32 MiB
  _Float16* ST = (_Float16*)(ws + 100663296);      // 64 MiB
  float2* stats = (float2*)(ws + 167772160);       // 128 KiB
  float2* part2 = (float2*)(ws + 167903232);       // 1 MiB (8 t-slices)

  static int smem_set = 0;
  if (!smem_set) {
    (void)hipFuncSetAttribute(
        reinterpret_cast<const void*>(&gemm8p<_Float16, false, true>),
        hipFuncAttributeMaxDynamicSharedMemorySize, 131072);
    (void)hipFuncSetAttribute(
        reinterpret_cast<const void*>(&gemm8p<float, true, false>),
        hipFuncAttributeMaxDynamicSharedMemorySize, 131072);
    smem_set = 1;
  }

  conv_enc<<<dim3(D / 64, SE / 64, B), 256, 0, stream>>>(enc, enc_h, enc_hT,
                                                         SE, D);
  conv_dec<<<dim3((size_t)B * SD * D / 2048), 256, 0, stream>>>(dec, dec_h);
  // ST[t][e] = dec_h @ enc_h^T  (M=t, N=e, K=D) + column stats partials
  gemm8p<_Float16, false, true>
      <<<dim3(SE / 256, SD / 256, B), 512, 131072, stream>>>(
          dec_h, enc_h, ST, nullptr, part2, D, (long)SD * D, (long)SE * D,
          (long)SD * SE, D, D, SE);
  stats_combine<<<dim3(64), 256, 0, stream>>>(part2, stats);
  // out[t][d] = exp(ST-m_e)*rl_e @ enc_hT^T-form  (M=t, N=d, K=e)
  gemm8p<float, true, false>
      <<<dim3(D / 256, SD / 256, B), 512, 131072, stream>>>(
          ST, enc_hT, out, stats, nullptr, SE, (long)SD * SE, (long)D * SE,
          (long)SD * D, SE, SE, D);
}

// Round 6
// 351.617 us; speedup vs baseline: 1.2090x; 1.2090x over previous
//
#include <hip/hip_runtime.h>

// ---------------------------------------------------------------------------
// Attention_20117626815094: c_t[b,t,d] = sum_e softmax_t(enc@dec^T)[e,t] * enc[e,d]
//   B=8, S_ENC=2048, S_DEC=2048, D=1024, fp32 in/out. f16 MFMA compute.
// Pipeline (v9 — LDS-bounce fused normalize, zero reg pressure; 4 kernels):
//   1. conv_enc:  enc fp32 -> enc_h [e][d] f16 AND enc_hT [d][e] f16
//   2. conv_dec:  dec fp32 -> dec_h [t][d] f16
//   3. gemm8p<STATS>: ST[t][e] = dec_h @ enc_h^T; epilogue emits per-block
//      column softmax partials (m, sum) from F16-ROUNDED accs (bit-identical
//      to ST -> self-normalizing softmax)
//   4. stats_combine: merge 8 t-slice partials -> c_e = -(m*log2e + log2(sum))
//   5. gemm8p<NORM>:  out[t][d] = exp2(ST*log2e + c_e) @ enc_hT^T-form
//      A staged RAW via global_load_lds (like plain path); transformed
//      IN-PLACE IN LDS at P1 of the consuming quad (transient regs only).
// ---------------------------------------------------------------------------

typedef _Float16 half8 __attribute__((ext_vector_type(8)));
typedef _Float16 half4v __attribute__((ext_vector_type(4)));
typedef float floatx4 __attribute__((ext_vector_type(4)));

__device__ __forceinline__ void async_load16(const _Float16* g, void* l) {
  __builtin_amdgcn_global_load_lds(
      (const __attribute__((address_space(1))) void*)g,
      (__attribute__((address_space(3))) void*)l, 16, 0, 0);
}

// ---- 256x256 8-phase pipelined GEMM: C = A @ Bt^T --------------------------
// A[M][K], Bt[N][K] row-major f16, k contiguous. C row-major OutT.
// 512 threads = 8 waves (2m x 4n); per-wave 128x64 out; BK=64; LDS 128 KiB
// (+8 KiB c-region for NORM).
// Swizzle: 16B chunk ck of row stored at ck^(row&7); frag reads use per-lane
// bases lb0/lb1 (all XOR folded), frag = +q*2048.
// Phases (quadrant order (0,0)(0,1)(1,1)(1,0); b0 regs live P1->P4):
//   P1: [NORM: in-LDS exp2 transform of this tile's A + barrier]
//       issue a-lo + b0 + b1 reads; mm(0,0)
//   P2: (no reads);                 mm(0,1)   [consumes a-lo, b1]
//   P3: issue a-hi; stage next B;   mm(1,1)   [B slot free after P2]
//   P4: stage next A;               mm(1,0); counted vmcnt(8)
// Ledger: quad t's end-vmcnt(8) guarantees tile t+1's 8 loads landed ->
// quad t+1's P1 transform/reads are safe; staging tile t+2 overwrites slots
// only after their last reads (A-hi at P3, B at P2) barrier-retired.
template <typename OutT, bool NORM, bool STATS>
__global__ __launch_bounds__(512, 2) void gemm8p(
    const _Float16* __restrict__ A, const _Float16* __restrict__ Bt,
    OutT* __restrict__ C, const float* __restrict__ cstat,
    float2* __restrict__ part_out, int K, long strideA, long strideB,
    long strideC, int ldA, int ldB, int ldC) {
  extern __shared__ char smem_[];
  const int tid = threadIdx.x;
  const int lane = tid & 63;
  const int wave = tid >> 6;
  const int wm = wave >> 2;  // 0..1
  const int wn = wave & 3;   // 0..3
  const int l15 = lane & 15;
  const int lh = lane >> 4;  // 0..3

  // XCD swizzle over the flat grid (nwg % 8 == 0)
  const int gx = gridDim.x, gxy = gridDim.x * gridDim.y;
  int fid = blockIdx.z * gxy + blockIdx.y * gx + blockIdx.x;
  const int nwg = gxy * gridDim.z;
  fid = (fid & 7) * (nwg >> 3) + (fid >> 3);
  const int b = fid / gxy;
  const int rem = fid - b * gxy;
  const int m0 = (rem / gx) * 256;
  const int n0 = (rem % gx) * 256;

  A += (long)b * strideA + (long)m0 * ldA;
  Bt += (long)b * strideB + (long)n0 * ldB;
  C += (long)b * strideC;
  const float* cstatB = NORM ? cstat + (size_t)b * 2048 : nullptr;

  // precomputed swizzled LDS read bases
  const int lb0 = l15 * 128 + ((lh ^ (l15 & 7)) << 4);
  const int lb1 = lb0 ^ 64;
  const char* aBuf[2] = {smem_ + wm * 16384, smem_ + 32768 + wm * 16384};
  const char* bBuf[2] = {
      smem_ + 65536 + (wn >> 1) * 16384 + (wn & 1) * 8192,
      smem_ + 98304 + (wn >> 1) * 16384 + (wn & 1) * 8192};
  char* aSlot[2] = {smem_, smem_ + 32768};
  char* bSlot[2] = {smem_ + 65536, smem_ + 98304};
  char* cLds = smem_ + 131072;  // NORM: 8 KiB of c_e floats

  // per-thread staging addresses (swizzle folded into the global source)
  const int srow = tid >> 3;
  const int skk = ((tid & 7) ^ (srow & 7)) << 3;
  const _Float16* Ast = A + (long)srow * ldA + skk;
  const _Float16* Bst = Bt + (long)srow * ldB + skk;
  const int dst = tid << 4;

  floatx4 acc[8][4] = {};
  half8 a[4][2], b0[2][2], b1[2][2];

  auto stage = [&](const _Float16* gs, int ld, int k0, char* slot) {
#pragma unroll
    for (int i = 0; i < 4; ++i)
      async_load16(gs + (long)(i * 64) * ld + k0, slot + i * 8192 + dst);
  };
  auto mm = [&](int mh, int nh, half8(&bb)[2][2]) {
    __builtin_amdgcn_s_setprio(1);
#pragma unroll
    for (int s = 0; s < 2; ++s)
#pragma unroll
      for (int q = 0; q < 4; ++q)
#pragma unroll
        for (int n = 0; n < 2; ++n)
          acc[mh * 4 + q][nh * 2 + n] = __builtin_amdgcn_mfma_f32_16x16x32_f16(
              a[q][s], bb[n][s], acc[mh * 4 + q][nh * 2 + n], 0, 0, 0);
    __builtin_amdgcn_s_setprio(0);
  };
  auto bar = [&]() { asm volatile("s_barrier" ::: "memory"); };

  auto quad4 = [&](int cur, int kst, int ebase, bool last) {
    const char* aB_ = aBuf[cur];
    const char* bB_ = bBuf[cur];
    // P1 pre-step (NORM): transform this tile's raw ST -> P, in place in LDS.
    // Each thread owns exactly the 4 chunks it staged (rows i*64+srow,
    // k-slice skk..skk+8 => e = ebase+skk+j). Transient regs only.
    if constexpr (NORM) {
      const int co = (ebase + skk) << 2;
      const float4 c0 = *(const float4*)(cLds + co);
      const float4 c1 = *(const float4*)(cLds + co + 16);
      const float cc[8] = {c0.x, c0.y, c0.z, c0.w, c1.x, c1.y, c1.z, c1.w};
#pragma unroll
      for (int i = 0; i < 4; ++i) {
        char* p = aSlot[cur] + i * 8192 + dst;
        half8 v = *(const half8*)p;
        half8 o;
#pragma unroll
        for (int j = 0; j < 8; ++j)
          o[j] = (_Float16)exp2f((float)v[j] * 1.44269504f + cc[j]);
        *(half8*)p = o;
      }
      asm volatile("s_waitcnt lgkmcnt(0)" ::: "memory");  // publish transform
      bar();
    }
    // P1: issue A-low (q=0..3) and ALL B frag reads; compute (0,0)
#pragma unroll
    for (int q = 0; q < 4; ++q) {
      a[q][0] = *(const half8*)(aB_ + lb0 + q * 2048);
      a[q][1] = *(const half8*)(aB_ + lb1 + q * 2048);
    }
#pragma unroll
    for (int n = 0; n < 2; ++n) {
      b0[n][0] = *(const half8*)(bB_ + lb0 + n * 2048);
      b0[n][1] = *(const half8*)(bB_ + lb1 + n * 2048);
      b1[n][0] = *(const half8*)(bB_ + lb0 + (n + 2) * 2048);
      b1[n][1] = *(const half8*)(bB_ + lb1 + (n + 2) * 2048);
    }
    bar();
    mm(0, 0, b0);
    bar();
    // P2: no reads (b1 issued in P1; a-lo still live for mm(0,1))
    bar();
    mm(0, 1, b1);
    bar();
    // P3: issue A-high (a-lo dead after mm(0,1)); stage next-tile B
    //     (B slot fully consumed after P2); compute (1,1)
#pragma unroll
    for (int q = 0; q < 4; ++q) {
      a[q][0] = *(const half8*)(aB_ + lb0 + (q + 4) * 2048);
      a[q][1] = *(const half8*)(aB_ + lb1 + (q + 4) * 2048);
    }
    if (kst >= 0) stage(Bst, ldB, kst, bSlot[cur]);
    bar();
    mm(1, 1, b1);
    bar();
    // P4: stage next-tile A (A slot fully consumed after P3); compute (1,0)
    if (kst >= 0) stage(Ast, ldA, kst, aSlot[cur]);
    mm(1, 0, b0);
    if (last)
      asm volatile("s_waitcnt vmcnt(0)" ::: "memory");
    else
      asm volatile("s_waitcnt vmcnt(8)" ::: "memory");
    bar();
  };

  // prologue: tiles 0,1 -> bufs 0,1; NORM also preloads the 2048 c-floats
  float4 cv;
  if constexpr (NORM) cv = *(const float4*)(cstatB + tid * 4);
  stage(Ast, ldA, 0, aSlot[0]);
  stage(Bst, ldB, 0, bSlot[0]);
  stage(Ast, ldA, 64, aSlot[1]);
  stage(Bst, ldB, 64, bSlot[1]);
  if constexpr (NORM) *(float4*)(cLds + (tid << 4)) = cv;
  asm volatile("s_waitcnt vmcnt(8) lgkmcnt(0)" ::: "memory");
  bar();

  const int NT = K >> 6;
  for (int i = 0; i < (NT >> 1) - 1; ++i) {
    quad4(0, (2 * i + 2) * 64, (2 * i) * 64, false);
    quad4(1, (2 * i + 3) * 64, (2 * i + 1) * 64, false);
  }
  quad4(0, -1, (NT - 2) * 64, true);
  quad4(1, -1, (NT - 1) * 64, true);

  // C/D layout (verified): col=lane&15, row=(lane>>4)*4+reg
#pragma unroll
  for (int mf = 0; mf < 8; ++mf) {
    const long r0 = (long)(m0 + wm * 128 + mf * 16 + lh * 4);
#pragma unroll
    for (int nf = 0; nf < 4; ++nf) {
      const int cc = n0 + wn * 64 + nf * 16 + l15;
#pragma unroll
      for (int rr = 0; rr < 4; ++rr)
        C[(r0 + rr) * ldC + cc] = (OutT)acc[mf][nf][rr];
    }
  }

  // Column softmax partials over this block's 256 rows. CRITICAL: computed
  // from the F16-ROUNDED accs -> bit-consistent with ST that the NORM pass
  // reads back -> softmax self-normalizes (dominant-entry rounding cancels).
  if constexpr (STATS) {
    float2* sm = (float2*)smem_;
#pragma unroll
    for (int nf = 0; nf < 4; ++nf) {
      float x16[8][4];
#pragma unroll
      for (int mf = 0; mf < 8; ++mf)
#pragma unroll
        for (int rr = 0; rr < 4; ++rr)
          x16[mf][rr] = (float)(_Float16)acc[mf][nf][rr];
      float mx = -1e30f;
#pragma unroll
      for (int mf = 0; mf < 8; ++mf)
#pragma unroll
        for (int rr = 0; rr < 4; ++rr) mx = fmaxf(mx, x16[mf][rr]);
      float ss = 0.f;
#pragma unroll
      for (int mf = 0; mf < 8; ++mf)
#pragma unroll
        for (int rr = 0; rr < 4; ++rr) ss += __expf(x16[mf][rr] - mx);
#pragma unroll
      for (int d = 16; d <= 32; d <<= 1) {
        const float om = __shfl_xor(mx, d, 64);
        const float os = __shfl_xor(ss, d, 64);
        const float m2 = fmaxf(mx, om);
        ss = ss * __expf(mx - m2) + os * __expf(om - m2);
        mx = m2;
      }
      if (lh == 0) sm[wm * 256 + wn * 64 + nf * 16 + l15] = make_float2(mx, ss);
    }
    __syncthreads();
    if (tid < 256) {
      const float2 a0 = sm[tid], a1 = sm[256 + tid];
      const float m2 = fmaxf(a0.x, a1.x);
      const float s2 =
          a0.y * __expf(a0.x - m2) + a1.y * __expf(a1.x - m2);
      part_out[(size_t)(m0 >> 8) * 16384 + (size_t)b * 2048 + n0 + tid] =
          make_float2(m2, s2);
    }
  }
}

// ---- enc convert + transpose (4x4 register micro-transpose) ---------------
__global__ __launch_bounds__(256) void conv_enc(const float* __restrict__ E,
                                                _Float16* __restrict__ Eh,
                                                _Float16* __restrict__ EhT,
                                                int Se, int D) {
  __shared__ _Float16 T[64][72];
  const int b = blockIdx.z;
  const int d0 = blockIdx.x * 64;
  const int e0 = blockIdx.y * 64;
  const float* Eb = E + (size_t)b * Se * D;
  _Float16* Ehb = Eh + (size_t)b * Se * D;
  _Float16* EhTb = EhT + (size_t)b * D * Se;
  const int tid = threadIdx.x;
  const int tx = tid & 15;
  const int ty = tid >> 4;

  half4v h[4];
#pragma unroll
  for (int r = 0; r < 4; ++r) {
    const int e = e0 + ty * 4 + r;
    float4 v = *(const float4*)(Eb + (size_t)e * D + d0 + tx * 4);
    h[r][0] = (_Float16)v.x; h[r][1] = (_Float16)v.y;
    h[r][2] = (_Float16)v.z; h[r][3] = (_Float16)v.w;
    *(half4v*)(Ehb + (size_t)e * D + d0 + tx * 4) = h[r];
  }
#pragma unroll
  for (int c = 0; c < 4; ++c) {
    half4v w;
#pragma unroll
    for (int r = 0; r < 4; ++r) w[r] = h[r][c];
    *(half4v*)&T[tx * 4 + c][ty * 4] = w;
  }
  __syncthreads();
#pragma unroll
  for (int p = 0; p < 2; ++p) {
    const int idx = tid + p * 256;
    const int row = idx >> 3;
    const int ck = idx & 7;
    *(half8*)(EhTb + (size_t)(d0 + row) * Se + e0 + ck * 8) =
        *(const half8*)&T[row][ck * 8];
  }
}

// ---- dec convert (16B stores) ---------------------------------------------
__global__ __launch_bounds__(256) void conv_dec(const float* __restrict__ X,
                                                _Float16* __restrict__ Y) {
  const size_t i = ((size_t)blockIdx.x * 256 + threadIdx.x) * 8;
  float4 a = *(const float4*)(X + i);
  float4 b = *(const float4*)(X + i + 4);
  half8 h;
  h[0] = (_Float16)a.x; h[1] = (_Float16)a.y;
  h[2] = (_Float16)a.z; h[3] = (_Float16)a.w;
  h[4] = (_Float16)b.x; h[5] = (_Float16)b.y;
  h[6] = (_Float16)b.z; h[7] = (_Float16)b.w;
  *(half8*)(Y + i) = h;
}

// ---- merge 8 t-slice partials -> c_e = -(m*log2e + log2(sum)) -------------
// gemm2 then computes P = exp2(v*log2e + c_e) == exp(v-m)/sum.
__global__ __launch_bounds__(256) void stats_combine(
    const float2* __restrict__ part, float* __restrict__ cstat) {
  const int idx = blockIdx.x * 256 + threadIdx.x;  // b*2048+e
  float2 a = part[idx];
#pragma unroll
  for (int tc = 1; tc < 8; ++tc) {
    const float2 o = part[tc * 16384 + idx];
    const float m2 = fmaxf(a.x, o.x);
    a.y = a.y * __expf(a.x - m2) + o.y * __expf(o.x - m2);
    a.x = m2;
  }
  cstat[idx] = -(a.x * 1.44269504f + log2f(a.y));
}

// ---------------------------------------------------------------------------
extern "C" void kernel_launch(void* const* d_in, const int* in_sizes, int n_in,
                              void* d_out, int out_size, void* d_ws,
                              size_t ws_size, hipStream_t stream) {
  const float* enc = (const float*)d_in[0];
  const float* dec = (const float*)d_in[1];
  float* out = (float*)d_out;

  const int B = 8, SE = 2048, SD = 2048, D = 1024;
  char* ws = (char*)d_ws;
  _Float16* enc_h = (_Float16*)ws;                 // 32 MiB
  _Float16* dec_h = (_Float16*)(ws + 33554432);    // 32 MiB
  _Float16* enc_hT = (_Float16*)(ws + 67108864);   // 32 MiB
  _Float16* ST = (_Float16*)(ws + 100663296);      // 64 MiB
  float* cstat = (float*)(ws + 167772160);         // 64 KiB
  float2* part2 = (float2*)(ws + 167903232);       // 1 MiB (8 t-slices)

  static int smem_set = 0;
  if (!smem_set) {
    (void)hipFuncSetAttribute(
        reinterpret_cast<const void*>(&gemm8p<_Float16, false, true>),
        hipFuncAttributeMaxDynamicSharedMemorySize, 131072);
    (void)hipFuncSetAttribute(
        reinterpret_cast<const void*>(&gemm8p<float, true, false>),
        hipFuncAttributeMaxDynamicSharedMemorySize, 139264);
    smem_set = 1;
  }

  conv_enc<<<dim3(D / 64, SE / 64, B), 256, 0, stream>>>(enc, enc_h, enc_hT,
                                                         SE, D);
  conv_dec<<<dim3((size_t)B * SD * D / 2048), 256, 0, stream>>>(dec, dec_h);
  // ST[t][e] = dec_h @ enc_h^T  (M=t, N=e, K=D) + column stats partials
  gemm8p<_Float16, false, true>
      <<<dim3(SE / 256, SD / 256, B), 512, 131072, stream>>>(
          dec_h, enc_h, ST, nullptr, part2, D, (long)SD * D, (long)SE * D,
          (long)SD * SE, D, D, SE);
  stats_combine<<<dim3(64), 256, 0, stream>>>(part2, cstat);
  // out[t][d] = exp2(ST*log2e + c_e) @ enc_hT^T-form  (M=t, N=d, K=e)
  gemm8p<float, true, false>
      <<<dim3(D / 256, SD / 256, B), 512, 139264, stream>>>(
          ST, enc_hT, out, cstat, nullptr, SE, (long)SD * SE, (long)D * SE,
          (long)SD * D, SE, SE, D);
}

// Round 7
// 320.991 us; speedup vs baseline: 1.3243x; 1.0954x over previous
//
#include <hip/hip_runtime.h>

// ---------------------------------------------------------------------------
// Attention_20117626815094: c_t[b,t,d] = sum_e softmax_t(enc@dec^T)[e,t] * enc[e,d]
//   B=8, S_ENC=2048, S_DEC=2048, D=1024, fp32 in/out. f16 MFMA compute.
// Pipeline (v10 — all-measured parts: fused STATS + plain GEMMs + streamer
// normalize; 6 kernels):
//   1. conv_enc:  enc fp32 -> enc_h [e][d] f16 AND enc_hT [d][e] f16
//   2. conv_dec:  dec fp32 -> dec_h [t][d] f16
//   3. gemm8p<STATS>: ST[t][e] = dec_h @ enc_h^T; epilogue emits per-block
//      column softmax partials (m, sum) from F16-ROUNDED accs (bit-identical
//      to ST -> self-normalizing softmax)
//   4. stats_combine: merge 8 t-slice partials -> c_e = -(m*log2e + log2(sum))
//   5. norm_stream: P[t][e] = exp2(ST*log2e + c_e)   (pure stream)
//   6. gemm8p:    out[t][d] = P @ enc_hT^T-form (fp32 out)
// ---------------------------------------------------------------------------

typedef _Float16 half8 __attribute__((ext_vector_type(8)));
typedef _Float16 half4v __attribute__((ext_vector_type(4)));
typedef float floatx4 __attribute__((ext_vector_type(4)));

__device__ __forceinline__ void async_load16(const _Float16* g, void* l) {
  __builtin_amdgcn_global_load_lds(
      (const __attribute__((address_space(1))) void*)g,
      (__attribute__((address_space(3))) void*)l, 16, 0, 0);
}

// ---- 256x256 8-phase pipelined GEMM: C = A @ Bt^T --------------------------
// A[M][K], Bt[N][K] row-major f16, k contiguous. C row-major OutT.
// 512 threads = 8 waves (2m x 4n); per-wave 128x64 out; BK=64; LDS 128 KiB.
// Swizzle: 16B chunk ck of row stored at ck^(row&7); frag reads use per-lane
// bases lb0/lb1 (all XOR folded), frag = +q*2048.
// Phases (quadrant order (0,0)(0,1)(1,1)(1,0); b0 regs live P1->P4):
//   P1: issue a-lo + b0 + b1 reads; mm(0,0)
//   P2: (no reads);                 mm(0,1)   [consumes a-lo, b1]
//   P3: issue a-hi; stage next B;   mm(1,1)   [B slot free after P2]
//   P4: stage next A;               mm(1,0); counted vmcnt(8)
// Ledger: end-of-quad-t vmcnt(8) retires tile t+1's 8 loads (oldest of <=16
// outstanding) -> quad t+1's reads are safe; tile t+2's 8 stay in flight.
template <typename OutT, bool STATS>
__global__ __launch_bounds__(512, 2) void gemm8p(
    const _Float16* __restrict__ A, const _Float16* __restrict__ Bt,
    OutT* __restrict__ C, float2* __restrict__ part_out, int K, long strideA,
    long strideB, long strideC, int ldA, int ldB, int ldC) {
  extern __shared__ char smem_[];
  const int tid = threadIdx.x;
  const int lane = tid & 63;
  const int wave = tid >> 6;
  const int wm = wave >> 2;  // 0..1
  const int wn = wave & 3;   // 0..3
  const int l15 = lane & 15;
  const int lh = lane >> 4;  // 0..3

  // XCD swizzle over the flat grid (nwg % 8 == 0)
  const int gx = gridDim.x, gxy = gridDim.x * gridDim.y;
  int fid = blockIdx.z * gxy + blockIdx.y * gx + blockIdx.x;
  const int nwg = gxy * gridDim.z;
  fid = (fid & 7) * (nwg >> 3) + (fid >> 3);
  const int b = fid / gxy;
  const int rem = fid - b * gxy;
  const int m0 = (rem / gx) * 256;
  const int n0 = (rem % gx) * 256;

  A += (long)b * strideA + (long)m0 * ldA;
  Bt += (long)b * strideB + (long)n0 * ldB;
  C += (long)b * strideC;

  // precomputed swizzled LDS read bases
  const int lb0 = l15 * 128 + ((lh ^ (l15 & 7)) << 4);
  const int lb1 = lb0 ^ 64;
  const char* aBuf[2] = {smem_ + wm * 16384, smem_ + 32768 + wm * 16384};
  const char* bBuf[2] = {
      smem_ + 65536 + (wn >> 1) * 16384 + (wn & 1) * 8192,
      smem_ + 98304 + (wn >> 1) * 16384 + (wn & 1) * 8192};
  char* aSlot[2] = {smem_, smem_ + 32768};
  char* bSlot[2] = {smem_ + 65536, smem_ + 98304};

  // per-thread staging addresses (swizzle folded into the global source)
  const int srow = tid >> 3;
  const int skk = ((tid & 7) ^ (srow & 7)) << 3;
  const _Float16* Ast = A + (long)srow * ldA + skk;
  const _Float16* Bst = Bt + (long)srow * ldB + skk;
  const int dst = tid << 4;

  floatx4 acc[8][4] = {};
  half8 a[4][2], b0[2][2], b1[2][2];

  auto stage = [&](const _Float16* gs, int ld, int k0, char* slot) {
#pragma unroll
    for (int i = 0; i < 4; ++i)
      async_load16(gs + (long)(i * 64) * ld + k0, slot + i * 8192 + dst);
  };
  auto mm = [&](int mh, int nh, half8(&bb)[2][2]) {
    __builtin_amdgcn_s_setprio(1);
#pragma unroll
    for (int s = 0; s < 2; ++s)
#pragma unroll
      for (int q = 0; q < 4; ++q)
#pragma unroll
        for (int n = 0; n < 2; ++n)
          acc[mh * 4 + q][nh * 2 + n] = __builtin_amdgcn_mfma_f32_16x16x32_f16(
              a[q][s], bb[n][s], acc[mh * 4 + q][nh * 2 + n], 0, 0, 0);
    __builtin_amdgcn_s_setprio(0);
  };
  auto bar = [&]() { asm volatile("s_barrier" ::: "memory"); };

  auto quad4 = [&](int cur, int kst, bool last) {
    const char* aB_ = aBuf[cur];
    const char* bB_ = bBuf[cur];
    // P1: issue A-low (q=0..3) and ALL B frag reads; compute (0,0)
#pragma unroll
    for (int q = 0; q < 4; ++q) {
      a[q][0] = *(const half8*)(aB_ + lb0 + q * 2048);
      a[q][1] = *(const half8*)(aB_ + lb1 + q * 2048);
    }
#pragma unroll
    for (int n = 0; n < 2; ++n) {
      b0[n][0] = *(const half8*)(bB_ + lb0 + n * 2048);
      b0[n][1] = *(const half8*)(bB_ + lb1 + n * 2048);
      b1[n][0] = *(const half8*)(bB_ + lb0 + (n + 2) * 2048);
      b1[n][1] = *(const half8*)(bB_ + lb1 + (n + 2) * 2048);
    }
    bar();
    mm(0, 0, b0);
    bar();
    // P2: no reads (b1 issued in P1; a-lo still live for mm(0,1))
    bar();
    mm(0, 1, b1);
    bar();
    // P3: issue A-high (a-lo dead after mm(0,1)); stage next-tile B
    //     (B slot fully consumed after P2); compute (1,1)
#pragma unroll
    for (int q = 0; q < 4; ++q) {
      a[q][0] = *(const half8*)(aB_ + lb0 + (q + 4) * 2048);
      a[q][1] = *(const half8*)(aB_ + lb1 + (q + 4) * 2048);
    }
    if (kst >= 0) stage(Bst, ldB, kst, bSlot[cur]);
    bar();
    mm(1, 1, b1);
    bar();
    // P4: stage next-tile A (A slot fully consumed after P3); compute (1,0)
    if (kst >= 0) stage(Ast, ldA, kst, aSlot[cur]);
    mm(1, 0, b0);
    if (last)
      asm volatile("s_waitcnt vmcnt(0)" ::: "memory");
    else
      asm volatile("s_waitcnt vmcnt(8)" ::: "memory");
    bar();
  };

  // prologue: tiles 0,1 -> bufs 0,1; drain tile0's 8, keep tile1 in flight
  stage(Ast, ldA, 0, aSlot[0]);
  stage(Bst, ldB, 0, bSlot[0]);
  stage(Ast, ldA, 64, aSlot[1]);
  stage(Bst, ldB, 64, bSlot[1]);
  asm volatile("s_waitcnt vmcnt(8)" ::: "memory");
  bar();

  const int NT = K >> 6;
  for (int i = 0; i < (NT >> 1) - 1; ++i) {
    quad4(0, (2 * i + 2) * 64, false);
    quad4(1, (2 * i + 3) * 64, false);
  }
  quad4(0, -1, true);  // vmcnt(0): last tile must land before reading buf1
  quad4(1, -1, true);

  // C/D layout (verified): col=lane&15, row=(lane>>4)*4+reg
#pragma unroll
  for (int mf = 0; mf < 8; ++mf) {
    const long r0 = (long)(m0 + wm * 128 + mf * 16 + lh * 4);
#pragma unroll
    for (int nf = 0; nf < 4; ++nf) {
      const int cc = n0 + wn * 64 + nf * 16 + l15;
#pragma unroll
      for (int rr = 0; rr < 4; ++rr)
        C[(r0 + rr) * ldC + cc] = (OutT)acc[mf][nf][rr];
    }
  }

  // Column softmax partials over this block's 256 rows. CRITICAL: computed
  // from the F16-ROUNDED accs -> bit-consistent with the ST values the
  // normalize pass reads back -> softmax self-normalizes (dominant-entry
  // rounding cancels; this is what keeps absmax at the 0.078 baseline).
  if constexpr (STATS) {
    float2* sm = (float2*)smem_;
#pragma unroll
    for (int nf = 0; nf < 4; ++nf) {
      float x16[8][4];
#pragma unroll
      for (int mf = 0; mf < 8; ++mf)
#pragma unroll
        for (int rr = 0; rr < 4; ++rr)
          x16[mf][rr] = (float)(_Float16)acc[mf][nf][rr];
      float mx = -1e30f;
#pragma unroll
      for (int mf = 0; mf < 8; ++mf)
#pragma unroll
        for (int rr = 0; rr < 4; ++rr) mx = fmaxf(mx, x16[mf][rr]);
      float ss = 0.f;
#pragma unroll
      for (int mf = 0; mf < 8; ++mf)
#pragma unroll
        for (int rr = 0; rr < 4; ++rr) ss += __expf(x16[mf][rr] - mx);
#pragma unroll
      for (int d = 16; d <= 32; d <<= 1) {
        const float om = __shfl_xor(mx, d, 64);
        const float os = __shfl_xor(ss, d, 64);
        const float m2 = fmaxf(mx, om);
        ss = ss * __expf(mx - m2) + os * __expf(om - m2);
        mx = m2;
      }
      if (lh == 0) sm[wm * 256 + wn * 64 + nf * 16 + l15] = make_float2(mx, ss);
    }
    __syncthreads();
    if (tid < 256) {
      const float2 a0 = sm[tid], a1 = sm[256 + tid];
      const float m2 = fmaxf(a0.x, a1.x);
      const float s2 =
          a0.y * __expf(a0.x - m2) + a1.y * __expf(a1.x - m2);
      part_out[(size_t)(m0 >> 8) * 16384 + (size_t)b * 2048 + n0 + tid] =
          make_float2(m2, s2);
    }
  }
}

// ---- enc convert + transpose (4x4 register micro-transpose) ---------------
__global__ __launch_bounds__(256) void conv_enc(const float* __restrict__ E,
                                                _Float16* __restrict__ Eh,
                                                _Float16* __restrict__ EhT,
                                                int Se, int D) {
  __shared__ _Float16 T[64][72];
  const int b = blockIdx.z;
  const int d0 = blockIdx.x * 64;
  const int e0 = blockIdx.y * 64;
  const float* Eb = E + (size_t)b * Se * D;
  _Float16* Ehb = Eh + (size_t)b * Se * D;
  _Float16* EhTb = EhT + (size_t)b * D * Se;
  const int tid = threadIdx.x;
  const int tx = tid & 15;
  const int ty = tid >> 4;

  half4v h[4];
#pragma unroll
  for (int r = 0; r < 4; ++r) {
    const int e = e0 + ty * 4 + r;
    float4 v = *(const float4*)(Eb + (size_t)e * D + d0 + tx * 4);
    h[r][0] = (_Float16)v.x; h[r][1] = (_Float16)v.y;
    h[r][2] = (_Float16)v.z; h[r][3] = (_Float16)v.w;
    *(half4v*)(Ehb + (size_t)e * D + d0 + tx * 4) = h[r];
  }
#pragma unroll
  for (int c = 0; c < 4; ++c) {
    half4v w;
#pragma unroll
    for (int r = 0; r < 4; ++r) w[r] = h[r][c];
    *(half4v*)&T[tx * 4 + c][ty * 4] = w;
  }
  __syncthreads();
#pragma unroll
  for (int p = 0; p < 2; ++p) {
    const int idx = tid + p * 256;
    const int row = idx >> 3;
    const int ck = idx & 7;
    *(half8*)(EhTb + (size_t)(d0 + row) * Se + e0 + ck * 8) =
        *(const half8*)&T[row][ck * 8];
  }
}

// ---- dec convert (16B stores) ---------------------------------------------
__global__ __launch_bounds__(256) void conv_dec(const float* __restrict__ X,
                                                _Float16* __restrict__ Y) {
  const size_t i = ((size_t)blockIdx.x * 256 + threadIdx.x) * 8;
  float4 a = *(const float4*)(X + i);
  float4 b = *(const float4*)(X + i + 4);
  half8 h;
  h[0] = (_Float16)a.x; h[1] = (_Float16)a.y;
  h[2] = (_Float16)a.z; h[3] = (_Float16)a.w;
  h[4] = (_Float16)b.x; h[5] = (_Float16)b.y;
  h[6] = (_Float16)b.z; h[7] = (_Float16)b.w;
  *(half8*)(Y + i) = h;
}

// ---- merge 8 t-slice partials -> c_e = -(m*log2e + log2(sum)) -------------
// norm_stream then computes P = exp2(v*log2e + c_e) == exp(v-m)/sum.
__global__ __launch_bounds__(256) void stats_combine(
    const float2* __restrict__ part, float* __restrict__ cstat) {
  const int idx = blockIdx.x * 256 + threadIdx.x;  // b*2048+e
  float2 a = part[idx];
#pragma unroll
  for (int tc = 1; tc < 8; ++tc) {
    const float2 o = part[tc * 16384 + idx];
    const float m2 = fmaxf(a.x, o.x);
    a.y = a.y * __expf(a.x - m2) + o.y * __expf(o.x - m2);
    a.x = m2;
  }
  cstat[idx] = -(a.x * 1.44269504f + log2f(a.y));
}

// ---- streaming normalize: P[t][e] = exp2(ST*log2e + c_e) ------------------
// grid: (512, 8); block 256; 4 t-rows per block, cstat reused across rows.
__global__ __launch_bounds__(256) void norm_stream(
    const _Float16* __restrict__ ST, const float* __restrict__ cstat,
    _Float16* __restrict__ P) {
  const int b = blockIdx.y;
  const int t0 = blockIdx.x * 4;
  const int e = threadIdx.x * 8;
  float c_[8];
  *(float4*)c_ = *(const float4*)(cstat + (size_t)b * 2048 + e);
  *(float4*)(c_ + 4) = *(const float4*)(cstat + (size_t)b * 2048 + e + 4);
  const size_t base = ((size_t)b * 2048 + t0) * 2048 + e;
#pragma unroll
  for (int r = 0; r < 4; ++r) {
    half8 v = *(const half8*)(ST + base + (size_t)r * 2048);
    half8 o;
#pragma unroll
    for (int j = 0; j < 8; ++j)
      o[j] = (_Float16)exp2f((float)v[j] * 1.44269504f + c_[j]);
    *(half8*)(P + base + (size_t)r * 2048) = o;
  }
}

// ---------------------------------------------------------------------------
extern "C" void kernel_launch(void* const* d_in, const int* in_sizes, int n_in,
                              void* d_out, int out_size, void* d_ws,
                              size_t ws_size, hipStream_t stream) {
  const float* enc = (const float*)d_in[0];
  const float* dec = (const float*)d_in[1];
  float* out = (float*)d_out;

  const int B = 8, SE = 2048, SD = 2048, D = 1024;
  char* ws = (char*)d_ws;
  _Float16* enc_h = (_Float16*)ws;                 // 32 MiB (dead after gemm1)
  _Float16* dec_h = (_Float16*)(ws + 33554432);    // 32 MiB (dead after gemm1)
  _Float16* P = (_Float16*)ws;                     // 64 MiB (reuses enc/dec_h)
  _Float16* enc_hT = (_Float16*)(ws + 67108864);   // 32 MiB
  _Float16* ST = (_Float16*)(ws + 100663296);      // 64 MiB
  float* cstat = (float*)(ws + 167772160);         // 64 KiB
  float2* part2 = (float2*)(ws + 167903232);       // 1 MiB (8 t-slices)

  static int smem_set = 0;
  if (!smem_set) {
    (void)hipFuncSetAttribute(
        reinterpret_cast<const void*>(&gemm8p<_Float16, true>),
        hipFuncAttributeMaxDynamicSharedMemorySize, 131072);
    (void)hipFuncSetAttribute(
        reinterpret_cast<const void*>(&gemm8p<float, false>),
        hipFuncAttributeMaxDynamicSharedMemorySize, 131072);
    smem_set = 1;
  }

  conv_enc<<<dim3(D / 64, SE / 64, B), 256, 0, stream>>>(enc, enc_h, enc_hT,
                                                         SE, D);
  conv_dec<<<dim3((size_t)B * SD * D / 2048), 256, 0, stream>>>(dec, dec_h);
  // ST[t][e] = dec_h @ enc_h^T  (M=t, N=e, K=D) + column stats partials
  gemm8p<_Float16, true><<<dim3(SE / 256, SD / 256, B), 512, 131072, stream>>>(
      dec_h, enc_h, ST, part2, D, (long)SD * D, (long)SE * D, (long)SD * SE,
      D, D, SE);
  stats_combine<<<dim3(64), 256, 0, stream>>>(part2, cstat);
  norm_stream<<<dim3(512, B), 256, 0, stream>>>(ST, cstat, P);
  // out[t][d] = P @ enc_hT^T-form  (M=t, N=d, K=e)
  gemm8p<float, false><<<dim3(D / 256, SD / 256, B), 512, 131072, stream>>>(
      P, enc_hT, out, nullptr, SE, (long)SD * SE, (long)D * SE, (long)SD * D,
      SE, SE, D);
}